// Round 19
// baseline (262.304 us; speedup 1.0000x reference)
//
#include <hip/hip_runtime.h>

typedef __attribute__((ext_vector_type(4))) float f32x4;
typedef __attribute__((ext_vector_type(8))) short s16x8;
typedef __attribute__((ext_vector_type(8))) __bf16 bf16x8;
typedef unsigned short u16;

// HW bf16 convert (v_cvt_pk_bf16_f32, RTNE) -- was a 5-op manual bit hack
__device__ __forceinline__ u16 f2b(float f) {
  return __builtin_bit_cast(u16, (__bf16)f);
}
__device__ __forceinline__ float b2f(u16 u) {
  union { unsigned u; float f; } x; x.u = ((unsigned)u) << 16;
  return x.f;
}
__device__ __forceinline__ void gld16(const void* g, void* l) {
  __builtin_amdgcn_global_load_lds(
      (const __attribute__((address_space(1))) unsigned int*)g,
      (__attribute__((address_space(3))) unsigned int*)l, 16, 0, 0);
}
__device__ __forceinline__ f32x4 mfma_bf16(s16x8 a, s16x8 b, f32x4 c) {
  return __builtin_amdgcn_mfma_f32_16x16x32_bf16(
      __builtin_bit_cast(bf16x8, a), __builtin_bit_cast(bf16x8, b), c, 0, 0, 0);
}

#define BAR() asm volatile("s_barrier" ::: "memory")

// -------- merged preprocessing: 6 weight transposes (z<6) + fp32->bf16 convert (z=6)
__global__ void k_prep(const float* __restrict__ hs, const float* __restrict__ ehs,
                       const float* __restrict__ iph,
                       const float* Wk, const float* Wv, const float* Wkip,
                       const float* Wvip, const float* Wq, const float* Wo,
                       u16* __restrict__ hsb, u16* __restrict__ ehsb,
                       u16* __restrict__ ipb,
                       u16* TK, u16* TV, u16* TKip, u16* TVip, u16* TQ, u16* TO) {
  const int z = blockIdx.z;
  if (z < 6) {
    const float* W = (z == 0) ? Wk : (z == 1) ? Wv : (z == 2) ? Wkip
                    : (z == 3) ? Wvip : (z == 4) ? Wq : Wo;
    u16* T = (z == 0) ? TK : (z == 1) ? TV : (z == 2) ? TKip
            : (z == 3) ? TVip : (z == 4) ? TQ : TO;
    const int K = (z < 4) ? 2048 : 1280;
    const int N = 1280;
    __shared__ float tile[32][33];
    int n0 = blockIdx.x * 32, k0 = blockIdx.y * 32;
    if (k0 >= K) return;
    int tx = threadIdx.x & 31, ty = threadIdx.x >> 5;
#pragma unroll
    for (int i = 0; i < 32; i += 8)
      tile[ty + i][tx] = W[(size_t)(k0 + ty + i) * N + n0 + tx];
    __syncthreads();
#pragma unroll
    for (int i = 0; i < 32; i += 8)
      T[(size_t)(n0 + ty + i) * K + k0 + tx] = f2b(tile[tx][ty + i]);
  } else {
    const int n1 = 16384 * 1280 / 4, n2 = 308 * 2048 / 4, n3 = 64 * 2048 / 4;
    const int ntot = n1 + n2 + n3;
    const int stride = 40 * 64 * 256;
    for (int i = (blockIdx.y * 40 + blockIdx.x) * 256 + threadIdx.x; i < ntot;
         i += stride) {
      const float* src; u16* dst; int j = i;
      if (i < n1) { src = hs; dst = hsb; }
      else if (i < n1 + n2) { src = ehs; dst = ehsb; j = i - n1; }
      else { src = iph; dst = ipb; j = i - n1 - n2; }
      float4 v = ((const float4*)src)[j];
      ushort4 o;
      o.x = f2b(v.x); o.y = f2b(v.y); o.z = f2b(v.z); o.w = f2b(v.w);
      ((ushort4*)dst)[j] = o;
    }
  }
}

// ---------------- small-GEMM core (128x128 tile, RING-5 prefetch), K/V projections ---
__device__ __forceinline__ void gemm_core0(
    const u16* __restrict__ A, const u16* __restrict__ BT,
    int M, int N, int K, u16* __restrict__ outb, int m0, int n0) {
  const int tid = threadIdx.x;
  const int l = tid & 63;
  const int w = tid >> 6;
  const int wr = w >> 1, wc = w & 1;
  __shared__ u16 As[5][4096];
  __shared__ u16 Bs[5][4096];
  f32x4 acc[4][4] = {};

  const int o0 = tid * 16;
  const int o1 = o0 + 4096;
  const int ra0 = o0 >> 6, ca0 = (o0 & 63) >> 1;
  const int ra1 = o1 >> 6, ca1 = (o1 & 63) >> 1;
  int ga0 = m0 + ra0; if (ga0 >= M) ga0 = M - 1;
  int ga1 = m0 + ra1; if (ga1 >= M) ga1 = M - 1;
  const u16* Ar0 = A + (size_t)ga0 * K + ca0;
  const u16* Ar1 = A + (size_t)ga1 * K + ca1;
  const u16* Br0 = BT + (size_t)(n0 + ra0) * K + ca0;
  const u16* Br1 = BT + (size_t)(n0 + ra1) * K + ca1;

  const int KT = K >> 5;
#define SSTAGE(s, kt)                                 \
  {                                                   \
    const int k0_ = (kt) << 5;                        \
    gld16(Ar0 + k0_, &As[s][o0 >> 1]);                \
    gld16(Ar1 + k0_, &As[s][o1 >> 1]);                \
    gld16(Br0 + k0_, &Bs[s][o0 >> 1]);                \
    gld16(Br1 + k0_, &Bs[s][o1 >> 1]);                \
  }
  SSTAGE(0, 0);
  SSTAGE(1, 1);
  SSTAGE(2, 2);
  SSTAGE(3, 3);
  asm volatile("s_waitcnt vmcnt(12)" ::: "memory");
  BAR();

  int slot = 0, s4 = 4;
  for (int j = 0; j < KT; ++j) {
    if (j + 4 < KT) SSTAGE(s4, j + 4);
    s16x8 af[4], bfr[4];
#pragma unroll
    for (int mi = 0; mi < 4; ++mi)
      af[mi] = *(const s16x8*)&As[slot][(wr * 64 + mi * 16 + (l & 15)) * 32 + (l >> 4) * 8];
#pragma unroll
    for (int ni = 0; ni < 4; ++ni)
      bfr[ni] = *(const s16x8*)&Bs[slot][(wc * 64 + ni * 16 + (l & 15)) * 32 + (l >> 4) * 8];
#pragma unroll
    for (int mi = 0; mi < 4; ++mi)
#pragma unroll
      for (int ni = 0; ni < 4; ++ni)
        acc[mi][ni] = mfma_bf16(af[mi], bfr[ni], acc[mi][ni]);
    const int rem = KT - 2 - j;
    if (rem >= 3)      asm volatile("s_waitcnt vmcnt(12)" ::: "memory");
    else if (rem == 2) asm volatile("s_waitcnt vmcnt(8)" ::: "memory");
    else if (rem == 1) asm volatile("s_waitcnt vmcnt(4)" ::: "memory");
    else               asm volatile("s_waitcnt vmcnt(0)" ::: "memory");
    BAR();
    ++slot; if (slot >= 5) slot = 0;
    ++s4; if (s4 >= 5) s4 = 0;
  }

#pragma unroll
  for (int mi = 0; mi < 4; ++mi) {
    const int mbase = m0 + wr * 64 + mi * 16 + (l >> 4) * 4;
#pragma unroll
    for (int ni = 0; ni < 4; ++ni) {
      const int ncol = n0 + wc * 64 + ni * 16 + (l & 15);
#pragma unroll
      for (int r = 0; r < 4; ++r) {
        int m = mbase + r;
        if (m < M) outb[(size_t)m * N + ncol] = f2b(acc[mi][ni][r]);
      }
    }
  }
#undef SSTAGE
}

// the four K/V projections in one launch (z selects)
__global__ __launch_bounds__(256) void k_gemm_small4(
    const u16* __restrict__ ehsb, const u16* __restrict__ ipb,
    const u16* __restrict__ WkT, const u16* __restrict__ WvT,
    const u16* __restrict__ WkipT, const u16* __restrict__ WvipT,
    u16* kbuf, u16* vbuf, u16* kipb, u16* vipb) {
  const int z = blockIdx.z;
  const int M = (z < 2) ? 308 : 64;
  const int m0 = blockIdx.y * 128;
  if (m0 >= M) return;
  const u16* A = (z < 2) ? ehsb : ipb;
  const u16* BT = (z == 0) ? WkT : (z == 1) ? WvT : (z == 2) ? WkipT : WvipT;
  u16* out = (z == 0) ? kbuf : (z == 1) ? vbuf : (z == 2) ? kipb : vipb;
  gemm_core0(A, BT, M, 1280, 2048, out, m0, blockIdx.x * 128);
}

// ---------------- V / Vip transpose: [tok][h*64+d] -> vt[h][d][b][96/16] ------------
__global__ void k_vtrans(const u16* __restrict__ vbuf, const u16* __restrict__ vipb,
                         u16* __restrict__ vt, u16* __restrict__ vipt) {
  const int b = blockIdx.x, h = blockIdx.y, z = blockIdx.z;
  const int tid = threadIdx.x;
  __shared__ u16 tile[80][72];
  if (z == 0) {
    for (int s = tid; s < 80 * 8; s += 256) {
      int t = s >> 3, c = s & 7;
      int4 v = {0, 0, 0, 0};
      if (t < 77) v = *(const int4*)(vbuf + (size_t)(b * 77 + t) * 1280 + h * 64 + c * 8);
      *(int4*)&tile[t][c * 8] = v;
    }
    __syncthreads();
    for (int s = tid; s < 64 * 12; s += 256) {
      int d = s / 12, tc = s % 12;
      s16x8 v;
#pragma unroll
      for (int j = 0; j < 8; ++j) {
        int t = tc * 8 + j;
        v[j] = (t < 80) ? (short)tile[t][d] : (short)0;
      }
      *(s16x8*)(vt + ((size_t)(h * 64 + d) * 4 + b) * 96 + tc * 8) = v;
    }
  } else {
    for (int s = tid; s < 16 * 8; s += 256) {
      int t = s >> 3, c = s & 7;
      *(int4*)&tile[t][c * 8] =
          *(const int4*)(vipb + (size_t)(b * 16 + t) * 1280 + h * 64 + c * 8);
    }
    __syncthreads();
    for (int s = tid; s < 64 * 2; s += 256) {
      int d = s >> 1, tc = s & 1;
      s16x8 v;
#pragma unroll
      for (int j = 0; j < 8; ++j) v[j] = (short)tile[tc * 8 + j][d];
      *(s16x8*)(vipt + ((size_t)(h * 64 + d) * 4 + b) * 16 + tc * 8) = v;
    }
  }
}

// ---------------- big GEMM: 256x320 tile, BK=32, RING-4, ONE barrier per K-tile -----
// (R8 schedule verbatim -- best measured: 66 us, MfmaUtil 33, conflicts 0. FROZEN.)
template <int EPI>
__global__ __launch_bounds__(512, 1) void k_gemm256(
    const u16* __restrict__ A, const u16* __restrict__ BT,
    int N, int K, float alpha,
    u16* __restrict__ outb, float* __restrict__ outf,
    const float* __restrict__ bias, const u16* __restrict__ ipadd,
    int nbx) {
  __shared__ u16 lds[73728];
  const int tid = threadIdx.x, l = tid & 63, w = tid >> 6;
  const int lr = l & 15, lg = l >> 4;
  const int wr = w >> 2, wc = w & 3;
  const bool wlo = (w < 4);

  const int nwg = gridDim.x;
  const int q = nwg >> 3, r = nwg & 7;
  const int xcd = blockIdx.x & 7, lid = blockIdx.x >> 3;
  const int wg = (xcd < r) ? (xcd * (q + 1) + lid)
                           : (r * (q + 1) + (xcd - r) * q + lid);
  const int bm0 = (wg / nbx) * 256, bn0 = (wg % nbx) * 320;

  const int srow = tid >> 2;
  const int sslot = ((tid & 3) ^ ((srow >> 1) & 3)) * 8;
  const size_t aO0 = (size_t)(bm0 + srow) * K + sslot;
  const size_t aO1 = aO0 + (size_t)128 * K;
  const size_t bO0 = (size_t)(bn0 + srow) * K + sslot;
  const size_t bO1 = bO0 + (size_t)128 * K;
  const size_t bO2 = bO0 + (size_t)256 * K;
  const int d0 = tid * 8, d1 = (tid + 512) * 8, d2 = (tid + 1024) * 8;

  const int KT = K >> 5;
  f32x4 acc[8][5] = {};
  s16x8 bfv[5], afv[4];

  const int xsw = (lg ^ ((lr >> 1) & 3)) * 8;
  const int aRow = (wr * 128 + lr) * 32 + xsw;
  const int bRow = 32768 + (wc * 80 + lr) * 32 + xsw;

#define STAGE_A(slot, kt)                                              \
  {                                                                    \
    const int base_ = (slot) * 8192;                                   \
    const size_t go_ = (size_t)(kt) * 32;                              \
    gld16(A + aO0 + go_, &lds[base_ + d0]);                            \
    gld16(A + aO1 + go_, &lds[base_ + d1]);                            \
  }
#define STAGE_B(slot, kt)                                              \
  {                                                                    \
    const int base_ = 32768 + (slot) * 10240;                          \
    const size_t go_ = (size_t)(kt) * 32;                              \
    gld16(BT + bO0 + go_, &lds[base_ + d0]);                           \
    gld16(BT + bO1 + go_, &lds[base_ + d1]);                           \
    if (wlo) gld16(BT + bO2 + go_, &lds[base_ + d2]);                  \
  }
#define WAIT_DEEP()                                                    \
  {                                                                    \
    if (wlo) asm volatile("s_waitcnt vmcnt(10)" ::: "memory");         \
    else     asm volatile("s_waitcnt vmcnt(8)" ::: "memory");          \
  }
#define WAIT_MID()                                                     \
  {                                                                    \
    if (wlo) asm volatile("s_waitcnt vmcnt(5)" ::: "memory");          \
    else     asm volatile("s_waitcnt vmcnt(4)" ::: "memory");          \
  }
#define WAITVM0() asm volatile("s_waitcnt vmcnt(0)" ::: "memory")

  STAGE_A(0, 0); STAGE_B(0, 0);
  STAGE_A(1, 1); STAGE_B(1, 1);
  STAGE_A(2, 2); STAGE_B(2, 2);
  WAIT_DEEP();
  BAR();

  for (int j = 0; j < KT; ++j) {
    const int slot = j & 3;
    const int ab = slot * 8192;
    const int bb = slot * 10240;
    const bool pf = (j + 3 < KT);
    const int s3 = (j + 3) & 3;
#pragma unroll
    for (int ni = 0; ni < 5; ++ni)
      bfv[ni] = *(const s16x8*)&lds[bb + bRow + ni * 512];
#pragma unroll
    for (int mi = 0; mi < 4; ++mi)
      afv[mi] = *(const s16x8*)&lds[ab + aRow + mi * 512];
    if (pf) STAGE_A(s3, j + 3);
    __builtin_amdgcn_s_setprio(1);
#pragma unroll
    for (int mi = 0; mi < 4; ++mi)
#pragma unroll
      for (int ni = 0; ni < 5; ++ni)
        acc[mi][ni] = mfma_bf16(afv[mi], bfv[ni], acc[mi][ni]);
    __builtin_amdgcn_s_setprio(0);
#pragma unroll
    for (int mi = 0; mi < 4; ++mi)
      afv[mi] = *(const s16x8*)&lds[ab + aRow + (mi + 4) * 512];
    if (pf) STAGE_B(s3, j + 3);
    __builtin_amdgcn_s_setprio(1);
#pragma unroll
    for (int mi = 0; mi < 4; ++mi)
#pragma unroll
      for (int ni = 0; ni < 5; ++ni)
        acc[mi + 4][ni] = mfma_bf16(afv[mi], bfv[ni], acc[mi + 4][ni]);
    __builtin_amdgcn_s_setprio(0);
    if (pf) { WAIT_DEEP(); }
    else if (j == KT - 3) { WAIT_MID(); }
    else { WAITVM0(); }
    BAR();
  }

  WAITVM0();
  __syncthreads();

  if constexpr (EPI == 0) {
#pragma unroll
    for (int half = 0; half < 2; ++half) {
      if (half) __syncthreads();
      if (wr == half) {
#pragma unroll
        for (int mi = 0; mi < 8; ++mi) {
          const int row = mi * 16 + lg * 4;
#pragma unroll
          for (int ni = 0; ni < 5; ++ni) {
            const int col = wc * 80 + ni * 16 + lr;
#pragma unroll
            for (int rr = 0; rr < 4; ++rr)
              lds[(row + rr) * 320 + col] = f2b(acc[mi][ni][rr] * alpha);
          }
        }
      }
      __syncthreads();
      const int rbase = tid >> 3;
      const int cseg = tid & 7;
#pragma unroll
      for (int rr2 = 0; rr2 < 2; ++rr2)
#pragma unroll
        for (int jj = 0; jj < 5; ++jj) {
          const int row = rr2 * 64 + rbase;
          const int ch = cseg + jj * 8;
          *(int4*)(outb + (size_t)(bm0 + half * 128 + row) * N + bn0 + ch * 8) =
              *(const int4*)&lds[row * 320 + ch * 8];
        }
    }
  } else {
#pragma unroll
    for (int mi = 0; mi < 8; ++mi) {
      const int mrow = bm0 + wr * 128 + mi * 16 + lg * 4;
#pragma unroll
      for (int ni = 0; ni < 5; ++ni) {
        const int ncol = bn0 + wc * 80 + ni * 16 + lr;
#pragma unroll
        for (int rr = 0; rr < 4; ++rr) {
          const size_t idx = (size_t)(mrow + rr) * N + ncol;
          outf[idx] = acc[mi][ni][rr] + bias[ncol] + b2f(ipadd[idx]);
        }
      }
    }
  }
#undef STAGE_A
#undef STAGE_B
#undef WAIT_DEEP
#undef WAIT_MID
#undef WAITVM0
}

// ---------------- fused attention (main + IP): 128 q-rows, no-max softmax, ----------
// hoisted mask prefetch. grid (32, 20, 4), 512 threads.
__global__ __launch_bounds__(512, 4) void k_attn(
    const u16* __restrict__ Q,     // [16384][1280], pre-scaled by 1/8
    const u16* __restrict__ Kb,    // [308][1280]
    const u16* __restrict__ Kip,   // [64][1280]
    const u16* __restrict__ Vt,    // [h][d][b][96], cols 77..95 zero
    const u16* __restrict__ VipT,  // [h][d][b][16]
    const float* __restrict__ mask,  // [4096][77]
    u16* __restrict__ Oattn, u16* __restrict__ Oip) {
  const int qt = blockIdx.x, h = blockIdx.y, b = blockIdx.z;
  const int tid = threadIdx.x, l = tid & 63, w = tid >> 6;
  const int lr = l & 15, lg = l >> 4;
  const int r0 = w * 16;
  const int m0 = b * 4096 + qt * 128;

  __shared__ u16 S[34560];
  u16 (*Ks)[72] = (u16(*)[72]) & S[0];
  const int VT_OFF = 6912, VIP_OFF = 13568;
  u16 (*Ps)[104] = (u16(*)[104]) & S[16128];
  u16 (*P2s)[40] = (u16(*)[40]) & S[29440];

  const u16* qrow = Q + (size_t)(m0 + r0 + lr) * 1280 + h * 64;
  s16x8 aq0 = *(const s16x8*)(qrow + lg * 8);
  s16x8 aq1 = *(const s16x8*)(qrow + 32 + lg * 8);

  for (int s = tid; s < 96 * 8; s += 512) {
    const int row = s >> 3, seg = s & 7;
    int4 v = {0, 0, 0, 0};
    if (row < 77)
      v = *(const int4*)(Kb + (size_t)(b * 77 + row) * 1280 + h * 64 + seg * 8);
    else if (row >= 80)
      v = *(const int4*)(Kip + (size_t)(b * 16 + row - 80) * 1280 + h * 64 + seg * 8);
    *(int4*)&Ks[row][(seg ^ ((row >> 3) & 3)) * 8] = v;
  }
  for (int s = tid; s < 64 * 12; s += 512) {
    const int row = s / 12, c = s % 12;
    *(int4*)&S[VT_OFF + row * 104 + c * 8] =
        *(const int4*)(Vt + ((size_t)(h * 64 + row) * 4 + b) * 96 + c * 8);
  }
  for (int s = tid; s < 64 * 4; s += 512) {
    const int row = s >> 2, c = s & 3;
    int4 v = {0, 0, 0, 0};
    if (c >= 2)
      v = *(const int4*)(VipT + ((size_t)(h * 64 + row) * 4 + b) * 16 + (c - 2) * 8);
    *(int4*)&S[VIP_OFF + row * 40 + c * 8] = v;
  }

  // hoisted mask prefetch: overlap latency with staging drain + QK^T
  float mk[4][5];
#pragma unroll
  for (int r = 0; r < 4; ++r) {
    const int qg = qt * 128 + r0 + lg * 4 + r;
#pragma unroll
    for (int t5 = 0; t5 < 5; ++t5) {
      const int t = t5 * 16 + lr;
      mk[r][t5] = (t < 77) ? mask[qg * 77 + t] : 0.f;
    }
  }
  __syncthreads();

  f32x4 sc[5];
  f32x4 sip = {};
#pragma unroll
  for (int t5 = 0; t5 < 6; ++t5) {
    const int trow = t5 * 16 + lr;
    const int qz = (trow >> 3) & 3;
    s16x8 b0 = *(const s16x8*)&Ks[trow][(lg ^ qz) * 8];
    s16x8 b1 = *(const s16x8*)&Ks[trow][((lg + 4) ^ qz) * 8];
    f32x4 c = {};
    c = mfma_bf16(aq0, b0, c);
    c = mfma_bf16(aq1, b1, c);
    if (t5 < 5) sc[t5] = c; else sip = c;
  }

  // softmax WITHOUT max-subtraction (|S| <= ~18 << 88, f32 exp safe)
#pragma unroll
  for (int r = 0; r < 4; ++r) {
    float p[5], sm = 0.f;
#pragma unroll
    for (int t5 = 0; t5 < 5; ++t5) {
      bool valid = (t5 < 4) | (lr < 13);  // t = t5*16+lr < 77
      p[t5] = valid ? __expf(sc[t5][r]) : 0.f;
      sm += p[t5];
    }
    sm += __shfl_xor(sm, 1);
    sm += __shfl_xor(sm, 2);
    sm += __shfl_xor(sm, 4);
    sm += __shfl_xor(sm, 8);
    const float inv = 1.0f / sm;
    const int row = r0 + lg * 4 + r;
#pragma unroll
    for (int t5 = 0; t5 < 5; ++t5)
      Ps[row][t5 * 16 + lr] = f2b(p[t5] * inv * mk[r][t5]);
    Ps[row][80 + lr] = 0;

    float pi = __expf(sip[r]);
    float s2 = pi;
    s2 += __shfl_xor(s2, 1);
    s2 += __shfl_xor(s2, 2);
    s2 += __shfl_xor(s2, 4);
    s2 += __shfl_xor(s2, 8);
    P2s[row][lr] = 0;
    P2s[row][16 + lr] = f2b(pi / s2);
  }

  s16x8 ap[3];
#pragma unroll
  for (int ks = 0; ks < 3; ++ks)
    ap[ks] = *(const s16x8*)&Ps[r0 + lr][ks * 32 + lg * 8];
  s16x8 aip = *(const s16x8*)&P2s[r0 + lr][lg * 8];

  f32x4 om[4], oi[4];
#pragma unroll
  for (int nt = 0; nt < 4; ++nt) {
    const int vrow = nt * 16 + lr;
    f32x4 o = {};
#pragma unroll
    for (int ks = 0; ks < 3; ++ks) {
      s16x8 bv = *(const s16x8*)&S[VT_OFF + vrow * 104 + (ks * 4 + lg) * 8];
      o = mfma_bf16(ap[ks], bv, o);
    }
    s16x8 bip = *(const s16x8*)&S[VIP_OFF + vrow * 40 + lg * 8];
    f32x4 o2 = {};
    o2 = mfma_bf16(aip, bip, o2);
    om[nt] = o;
    oi[nt] = o2;
  }

  __syncthreads();  // all reads of Ks/VT/Ps done: reuse arena for output repack

  u16 (*Om)[72] = (u16(*)[72]) & S[0];
  u16 (*Oi)[72] = (u16(*)[72]) & S[16128];
#pragma unroll
  for (int nt = 0; nt < 4; ++nt)
#pragma unroll
    for (int r = 0; r < 4; ++r) {
      const int row = r0 + lg * 4 + r;
      const int d = nt * 16 + lr;
      Om[row][d] = f2b(om[nt][r]);
      Oi[row][d] = f2b(oi[nt][r]);
    }
  __syncthreads();

  for (int s = tid; s < 128 * 8; s += 512) {
    const int row = s >> 3, seg = s & 7;
    const size_t g = (size_t)(m0 + row) * 1280 + h * 64 + seg * 8;
    *(int4*)(Oattn + g) = *(const int4*)&Om[row][seg * 8];
    *(int4*)(Oip + g) = *(const int4*)&Oi[row][seg * 8];
  }
}

// ---------------- launch ----------------
extern "C" void kernel_launch(void* const* d_in, const int* in_sizes, int n_in,
                              void* d_out, int out_size, void* d_ws, size_t ws_size,
                              hipStream_t stream) {
  (void)in_sizes; (void)n_in; (void)out_size; (void)ws_size;
  const float* hs   = (const float*)d_in[0];
  const float* ehs  = (const float*)d_in[1];
  const float* iph  = (const float*)d_in[2];
  const float* mask = (const float*)d_in[3];
  const float* Wq   = (const float*)d_in[4];
  const float* Wk   = (const float*)d_in[5];
  const float* Wv   = (const float*)d_in[6];
  const float* Wo   = (const float*)d_in[7];
  const float* bo   = (const float*)d_in[8];
  const float* Wkip = (const float*)d_in[9];
  const float* Wvip = (const float*)d_in[10];
  float* out = (float*)d_out;

  char* ws = (char*)d_ws;
  size_t off = 0;
  auto alloc = [&](size_t bytes) {
    char* p = ws + off;
    off += (bytes + 255) & ~(size_t)255;
    return p;
  };
  u16* hsb   = (u16*)alloc(16384ull * 1280 * 2);  // reused as attn_out
  u16* qbuf  = (u16*)alloc(16384ull * 1280 * 2);
  u16* ipout = (u16*)alloc(16384ull * 1280 * 2);
  u16* WqT   = (u16*)alloc(1280ull * 1280 * 2);
  u16* WoT   = (u16*)alloc(1280ull * 1280 * 2);
  u16* WkT   = (u16*)alloc(1280ull * 2048 * 2);
  u16* WvT   = (u16*)alloc(1280ull * 2048 * 2);
  u16* WkipT = (u16*)alloc(1280ull * 2048 * 2);
  u16* WvipT = (u16*)alloc(1280ull * 2048 * 2);
  u16* ehsb  = (u16*)alloc(308ull * 2048 * 2);
  u16* ipb   = (u16*)alloc(64ull * 2048 * 2);
  u16* kbuf  = (u16*)alloc(308ull * 1280 * 2);
  u16* vbuf  = (u16*)alloc(308ull * 1280 * 2);
  u16* kipb  = (u16*)alloc(64ull * 1280 * 2);
  u16* vipb  = (u16*)alloc(64ull * 1280 * 2);
  u16* vt    = (u16*)alloc(1280ull * 4 * 96 * 2);
  u16* vipt  = (u16*)alloc(1280ull * 4 * 16 * 2);

  // merged preprocessing: transposes (z<6) + conversions (z=6)
  k_prep<<<dim3(40, 64, 7), 256, 0, stream>>>(hs, ehs, iph, Wk, Wv, Wkip, Wvip, Wq, Wo,
                                              hsb, ehsb, ipb,
                                              WkT, WvT, WkipT, WvipT, WqT, WoT);

  // Q projection (scale 1/8 baked in): 64 x 4 = 256 blocks, 1/CU
  k_gemm256<0><<<256, 512, 0, stream>>>(hsb, WqT, 1280, 1280, 0.125f,
                                        qbuf, nullptr, nullptr, nullptr, 4);
  // K/V/Kip/Vip projections in one launch (ring-5 prefetch core)
  k_gemm_small4<<<dim3(10, 3, 4), 256, 0, stream>>>(ehsb, ipb, WkT, WvT, WkipT, WvipT,
                                                    kbuf, vbuf, kipb, vipb);
  // V / Vip global transpose for attn's b128 PV path
  k_vtrans<<<dim3(4, 20, 2), 256, 0, stream>>>(vbuf, vipb, vt, vipt);

  // fused attention (main + IP). attn_out -> hsb.
  k_attn<<<dim3(32, 20, 4), 512, 0, stream>>>(qbuf, kbuf, kipb, vt, vipt, mask,
                                              hsb, ipout);

  // out = attn_out @ Wo + bo + ip_out
  k_gemm256<1><<<256, 512, 0, stream>>>(hsb, WoT, 1280, 1280, 1.f,
                                        nullptr, out, bo, ipout, 4);
}

// Round 20
// 256.474 us; speedup vs baseline: 1.0227x; 1.0227x over previous
//
#include <hip/hip_runtime.h>

typedef __attribute__((ext_vector_type(4))) float f32x4;
typedef __attribute__((ext_vector_type(8))) short s16x8;
typedef __attribute__((ext_vector_type(8))) __bf16 bf16x8;
typedef unsigned short u16;

// manual RTNE f32->bf16 (measured faster than the (__bf16) cast path in R19)
__device__ __forceinline__ u16 f2b(float f) {
  union { float f; unsigned u; } x; x.f = f;
  unsigned r = x.u + 0x7fffu + ((x.u >> 16) & 1u);
  return (u16)(r >> 16);
}
__device__ __forceinline__ float b2f(u16 u) {
  union { unsigned u; float f; } x; x.u = ((unsigned)u) << 16;
  return x.f;
}
__device__ __forceinline__ void gld16(const void* g, void* l) {
  __builtin_amdgcn_global_load_lds(
      (const __attribute__((address_space(1))) unsigned int*)g,
      (__attribute__((address_space(3))) unsigned int*)l, 16, 0, 0);
}
__device__ __forceinline__ f32x4 mfma_bf16(s16x8 a, s16x8 b, f32x4 c) {
  return __builtin_amdgcn_mfma_f32_16x16x32_bf16(
      __builtin_bit_cast(bf16x8, a), __builtin_bit_cast(bf16x8, b), c, 0, 0, 0);
}

#define BAR() asm volatile("s_barrier" ::: "memory")

// -------- merged preprocessing: 6 weight transposes (z<6) + fp32->bf16 convert (z=6)
__global__ void k_prep(const float* __restrict__ hs, const float* __restrict__ ehs,
                       const float* __restrict__ iph,
                       const float* Wk, const float* Wv, const float* Wkip,
                       const float* Wvip, const float* Wq, const float* Wo,
                       u16* __restrict__ hsb, u16* __restrict__ ehsb,
                       u16* __restrict__ ipb,
                       u16* TK, u16* TV, u16* TKip, u16* TVip, u16* TQ, u16* TO) {
  const int z = blockIdx.z;
  if (z < 6) {
    const float* W = (z == 0) ? Wk : (z == 1) ? Wv : (z == 2) ? Wkip
                    : (z == 3) ? Wvip : (z == 4) ? Wq : Wo;
    u16* T = (z == 0) ? TK : (z == 1) ? TV : (z == 2) ? TKip
            : (z == 3) ? TVip : (z == 4) ? TQ : TO;
    const int K = (z < 4) ? 2048 : 1280;
    const int N = 1280;
    __shared__ float tile[32][33];
    int n0 = blockIdx.x * 32, k0 = blockIdx.y * 32;
    if (k0 >= K) return;
    int tx = threadIdx.x & 31, ty = threadIdx.x >> 5;
#pragma unroll
    for (int i = 0; i < 32; i += 8)
      tile[ty + i][tx] = W[(size_t)(k0 + ty + i) * N + n0 + tx];
    __syncthreads();
#pragma unroll
    for (int i = 0; i < 32; i += 8)
      T[(size_t)(n0 + ty + i) * K + k0 + tx] = f2b(tile[tx][ty + i]);
  } else {
    const int n1 = 16384 * 1280 / 4, n2 = 308 * 2048 / 4, n3 = 64 * 2048 / 4;
    const int ntot = n1 + n2 + n3;
    const int stride = 40 * 64 * 256;
    for (int i = (blockIdx.y * 40 + blockIdx.x) * 256 + threadIdx.x; i < ntot;
         i += stride) {
      const float* src; u16* dst; int j = i;
      if (i < n1) { src = hs; dst = hsb; }
      else if (i < n1 + n2) { src = ehs; dst = ehsb; j = i - n1; }
      else { src = iph; dst = ipb; j = i - n1 - n2; }
      float4 v = ((const float4*)src)[j];
      ushort4 o;
      o.x = f2b(v.x); o.y = f2b(v.y); o.z = f2b(v.z); o.w = f2b(v.w);
      ((ushort4*)dst)[j] = o;
    }
  }
}

// ---------------- small-GEMM core (128x128 tile, RING-5 prefetch), K/V projections ---
__device__ __forceinline__ void gemm_core0(
    const u16* __restrict__ A, const u16* __restrict__ BT,
    int M, int N, int K, u16* __restrict__ outb, int m0, int n0) {
  const int tid = threadIdx.x;
  const int l = tid & 63;
  const int w = tid >> 6;
  const int wr = w >> 1, wc = w & 1;
  __shared__ u16 As[5][4096];
  __shared__ u16 Bs[5][4096];
  f32x4 acc[4][4] = {};

  const int o0 = tid * 16;
  const int o1 = o0 + 4096;
  const int ra0 = o0 >> 6, ca0 = (o0 & 63) >> 1;
  const int ra1 = o1 >> 6, ca1 = (o1 & 63) >> 1;
  int ga0 = m0 + ra0; if (ga0 >= M) ga0 = M - 1;
  int ga1 = m0 + ra1; if (ga1 >= M) ga1 = M - 1;
  const u16* Ar0 = A + (size_t)ga0 * K + ca0;
  const u16* Ar1 = A + (size_t)ga1 * K + ca1;
  const u16* Br0 = BT + (size_t)(n0 + ra0) * K + ca0;
  const u16* Br1 = BT + (size_t)(n0 + ra1) * K + ca1;

  const int KT = K >> 5;
#define SSTAGE(s, kt)                                 \
  {                                                   \
    const int k0_ = (kt) << 5;                        \
    gld16(Ar0 + k0_, &As[s][o0 >> 1]);                \
    gld16(Ar1 + k0_, &As[s][o1 >> 1]);                \
    gld16(Br0 + k0_, &Bs[s][o0 >> 1]);                \
    gld16(Br1 + k0_, &Bs[s][o1 >> 1]);                \
  }
  SSTAGE(0, 0);
  SSTAGE(1, 1);
  SSTAGE(2, 2);
  SSTAGE(3, 3);
  asm volatile("s_waitcnt vmcnt(12)" ::: "memory");
  BAR();

  int slot = 0, s4 = 4;
  for (int j = 0; j < KT; ++j) {
    if (j + 4 < KT) SSTAGE(s4, j + 4);
    s16x8 af[4], bfr[4];
#pragma unroll
    for (int mi = 0; mi < 4; ++mi)
      af[mi] = *(const s16x8*)&As[slot][(wr * 64 + mi * 16 + (l & 15)) * 32 + (l >> 4) * 8];
#pragma unroll
    for (int ni = 0; ni < 4; ++ni)
      bfr[ni] = *(const s16x8*)&Bs[slot][(wc * 64 + ni * 16 + (l & 15)) * 32 + (l >> 4) * 8];
#pragma unroll
    for (int mi = 0; mi < 4; ++mi)
#pragma unroll
      for (int ni = 0; ni < 4; ++ni)
        acc[mi][ni] = mfma_bf16(af[mi], bfr[ni], acc[mi][ni]);
    const int rem = KT - 2 - j;
    if (rem >= 3)      asm volatile("s_waitcnt vmcnt(12)" ::: "memory");
    else if (rem == 2) asm volatile("s_waitcnt vmcnt(8)" ::: "memory");
    else if (rem == 1) asm volatile("s_waitcnt vmcnt(4)" ::: "memory");
    else               asm volatile("s_waitcnt vmcnt(0)" ::: "memory");
    BAR();
    ++slot; if (slot >= 5) slot = 0;
    ++s4; if (s4 >= 5) s4 = 0;
  }

#pragma unroll
  for (int mi = 0; mi < 4; ++mi) {
    const int mbase = m0 + wr * 64 + mi * 16 + (l >> 4) * 4;
#pragma unroll
    for (int ni = 0; ni < 4; ++ni) {
      const int ncol = n0 + wc * 64 + ni * 16 + (l & 15);
#pragma unroll
      for (int r = 0; r < 4; ++r) {
        int m = mbase + r;
        if (m < M) outb[(size_t)m * N + ncol] = f2b(acc[mi][ni][r]);
      }
    }
  }
#undef SSTAGE
}

// the four K/V projections in one launch (z selects)
__global__ __launch_bounds__(256) void k_gemm_small4(
    const u16* __restrict__ ehsb, const u16* __restrict__ ipb,
    const u16* __restrict__ WkT, const u16* __restrict__ WvT,
    const u16* __restrict__ WkipT, const u16* __restrict__ WvipT,
    u16* kbuf, u16* vbuf, u16* kipb, u16* vipb) {
  const int z = blockIdx.z;
  const int M = (z < 2) ? 308 : 64;
  const int m0 = blockIdx.y * 128;
  if (m0 >= M) return;
  const u16* A = (z < 2) ? ehsb : ipb;
  const u16* BT = (z == 0) ? WkT : (z == 1) ? WvT : (z == 2) ? WkipT : WvipT;
  u16* out = (z == 0) ? kbuf : (z == 1) ? vbuf : (z == 2) ? kipb : vipb;
  gemm_core0(A, BT, M, 1280, 2048, out, m0, blockIdx.x * 128);
}

// ---------------- V / Vip transpose: [tok][h*64+d] -> vt[h][d][b][96/16] ------------
__global__ void k_vtrans(const u16* __restrict__ vbuf, const u16* __restrict__ vipb,
                         u16* __restrict__ vt, u16* __restrict__ vipt) {
  const int b = blockIdx.x, h = blockIdx.y, z = blockIdx.z;
  const int tid = threadIdx.x;
  __shared__ u16 tile[80][72];
  if (z == 0) {
    for (int s = tid; s < 80 * 8; s += 256) {
      int t = s >> 3, c = s & 7;
      int4 v = {0, 0, 0, 0};
      if (t < 77) v = *(const int4*)(vbuf + (size_t)(b * 77 + t) * 1280 + h * 64 + c * 8);
      *(int4*)&tile[t][c * 8] = v;
    }
    __syncthreads();
    for (int s = tid; s < 64 * 12; s += 256) {
      int d = s / 12, tc = s % 12;
      s16x8 v;
#pragma unroll
      for (int j = 0; j < 8; ++j) {
        int t = tc * 8 + j;
        v[j] = (t < 80) ? (short)tile[t][d] : (short)0;
      }
      *(s16x8*)(vt + ((size_t)(h * 64 + d) * 4 + b) * 96 + tc * 8) = v;
    }
  } else {
    for (int s = tid; s < 16 * 8; s += 256) {
      int t = s >> 3, c = s & 7;
      *(int4*)&tile[t][c * 8] =
          *(const int4*)(vipb + (size_t)(b * 16 + t) * 1280 + h * 64 + c * 8);
    }
    __syncthreads();
    for (int s = tid; s < 64 * 2; s += 256) {
      int d = s >> 1, tc = s & 1;
      s16x8 v;
#pragma unroll
      for (int j = 0; j < 8; ++j) v[j] = (short)tile[tc * 8 + j][d];
      *(s16x8*)(vipt + ((size_t)(h * 64 + d) * 4 + b) * 16 + tc * 8) = v;
    }
  }
}

// ---------------- big GEMM: 256x320 tile, BK=32, RING-4, ONE barrier per K-tile -----
// (R8 schedule verbatim -- best measured: 66 us, MfmaUtil 33, conflicts 0. FROZEN.)
template <int EPI>
__global__ __launch_bounds__(512, 1) void k_gemm256(
    const u16* __restrict__ A, const u16* __restrict__ BT,
    int N, int K, float alpha,
    u16* __restrict__ outb, float* __restrict__ outf,
    const float* __restrict__ bias, const u16* __restrict__ ipadd,
    int nbx) {
  __shared__ u16 lds[73728];
  const int tid = threadIdx.x, l = tid & 63, w = tid >> 6;
  const int lr = l & 15, lg = l >> 4;
  const int wr = w >> 2, wc = w & 3;
  const bool wlo = (w < 4);

  const int nwg = gridDim.x;
  const int q = nwg >> 3, r = nwg & 7;
  const int xcd = blockIdx.x & 7, lid = blockIdx.x >> 3;
  const int wg = (xcd < r) ? (xcd * (q + 1) + lid)
                           : (r * (q + 1) + (xcd - r) * q + lid);
  const int bm0 = (wg / nbx) * 256, bn0 = (wg % nbx) * 320;

  const int srow = tid >> 2;
  const int sslot = ((tid & 3) ^ ((srow >> 1) & 3)) * 8;
  const size_t aO0 = (size_t)(bm0 + srow) * K + sslot;
  const size_t aO1 = aO0 + (size_t)128 * K;
  const size_t bO0 = (size_t)(bn0 + srow) * K + sslot;
  const size_t bO1 = bO0 + (size_t)128 * K;
  const size_t bO2 = bO0 + (size_t)256 * K;
  const int d0 = tid * 8, d1 = (tid + 512) * 8, d2 = (tid + 1024) * 8;

  const int KT = K >> 5;
  f32x4 acc[8][5] = {};
  s16x8 bfv[5], afv[4];

  const int xsw = (lg ^ ((lr >> 1) & 3)) * 8;
  const int aRow = (wr * 128 + lr) * 32 + xsw;
  const int bRow = 32768 + (wc * 80 + lr) * 32 + xsw;

#define STAGE_A(slot, kt)                                              \
  {                                                                    \
    const int base_ = (slot) * 8192;                                   \
    const size_t go_ = (size_t)(kt) * 32;                              \
    gld16(A + aO0 + go_, &lds[base_ + d0]);                            \
    gld16(A + aO1 + go_, &lds[base_ + d1]);                            \
  }
#define STAGE_B(slot, kt)                                              \
  {                                                                    \
    const int base_ = 32768 + (slot) * 10240;                          \
    const size_t go_ = (size_t)(kt) * 32;                              \
    gld16(BT + bO0 + go_, &lds[base_ + d0]);                           \
    gld16(BT + bO1 + go_, &lds[base_ + d1]);                           \
    if (wlo) gld16(BT + bO2 + go_, &lds[base_ + d2]);                  \
  }
#define WAIT_DEEP()                                                    \
  {                                                                    \
    if (wlo) asm volatile("s_waitcnt vmcnt(10)" ::: "memory");         \
    else     asm volatile("s_waitcnt vmcnt(8)" ::: "memory");          \
  }
#define WAIT_MID()                                                     \
  {                                                                    \
    if (wlo) asm volatile("s_waitcnt vmcnt(5)" ::: "memory");          \
    else     asm volatile("s_waitcnt vmcnt(4)" ::: "memory");          \
  }
#define WAITVM0() asm volatile("s_waitcnt vmcnt(0)" ::: "memory")

  STAGE_A(0, 0); STAGE_B(0, 0);
  STAGE_A(1, 1); STAGE_B(1, 1);
  STAGE_A(2, 2); STAGE_B(2, 2);
  WAIT_DEEP();
  BAR();

  for (int j = 0; j < KT; ++j) {
    const int slot = j & 3;
    const int ab = slot * 8192;
    const int bb = slot * 10240;
    const bool pf = (j + 3 < KT);
    const int s3 = (j + 3) & 3;
#pragma unroll
    for (int ni = 0; ni < 5; ++ni)
      bfv[ni] = *(const s16x8*)&lds[bb + bRow + ni * 512];
#pragma unroll
    for (int mi = 0; mi < 4; ++mi)
      afv[mi] = *(const s16x8*)&lds[ab + aRow + mi * 512];
    if (pf) STAGE_A(s3, j + 3);
    __builtin_amdgcn_s_setprio(1);
#pragma unroll
    for (int mi = 0; mi < 4; ++mi)
#pragma unroll
      for (int ni = 0; ni < 5; ++ni)
        acc[mi][ni] = mfma_bf16(afv[mi], bfv[ni], acc[mi][ni]);
    __builtin_amdgcn_s_setprio(0);
#pragma unroll
    for (int mi = 0; mi < 4; ++mi)
      afv[mi] = *(const s16x8*)&lds[ab + aRow + (mi + 4) * 512];
    if (pf) STAGE_B(s3, j + 3);
    __builtin_amdgcn_s_setprio(1);
#pragma unroll
    for (int mi = 0; mi < 4; ++mi)
#pragma unroll
      for (int ni = 0; ni < 5; ++ni)
        acc[mi + 4][ni] = mfma_bf16(afv[mi], bfv[ni], acc[mi + 4][ni]);
    __builtin_amdgcn_s_setprio(0);
    if (pf) { WAIT_DEEP(); }
    else if (j == KT - 3) { WAIT_MID(); }
    else { WAITVM0(); }
    BAR();
  }

  WAITVM0();
  __syncthreads();

  if constexpr (EPI == 0) {
#pragma unroll
    for (int half = 0; half < 2; ++half) {
      if (half) __syncthreads();
      if (wr == half) {
#pragma unroll
        for (int mi = 0; mi < 8; ++mi) {
          const int row = mi * 16 + lg * 4;
#pragma unroll
          for (int ni = 0; ni < 5; ++ni) {
            const int col = wc * 80 + ni * 16 + lr;
#pragma unroll
            for (int rr = 0; rr < 4; ++rr)
              lds[(row + rr) * 320 + col] = f2b(acc[mi][ni][rr] * alpha);
          }
        }
      }
      __syncthreads();
      const int rbase = tid >> 3;
      const int cseg = tid & 7;
#pragma unroll
      for (int rr2 = 0; rr2 < 2; ++rr2)
#pragma unroll
        for (int jj = 0; jj < 5; ++jj) {
          const int row = rr2 * 64 + rbase;
          const int ch = cseg + jj * 8;
          *(int4*)(outb + (size_t)(bm0 + half * 128 + row) * N + bn0 + ch * 8) =
              *(const int4*)&lds[row * 320 + ch * 8];
        }
    }
  } else {
#pragma unroll
    for (int mi = 0; mi < 8; ++mi) {
      const int mrow = bm0 + wr * 128 + mi * 16 + lg * 4;
#pragma unroll
      for (int ni = 0; ni < 5; ++ni) {
        const int ncol = bn0 + wc * 80 + ni * 16 + lr;
#pragma unroll
        for (int rr = 0; rr < 4; ++rr) {
          const size_t idx = (size_t)(mrow + rr) * N + ncol;
          outf[idx] = acc[mi][ni][rr] + bias[ncol] + b2f(ipadd[idx]);
        }
      }
    }
  }
#undef STAGE_A
#undef STAGE_B
#undef WAIT_DEEP
#undef WAIT_MID
#undef WAITVM0
}

// ---------------- fused attention (main + IP): 128 q-rows, no-max softmax, ----------
// hoisted mask prefetch. grid (32, 20, 4), 512 threads.
__global__ __launch_bounds__(512, 4) void k_attn(
    const u16* __restrict__ Q,     // [16384][1280], pre-scaled by 1/8
    const u16* __restrict__ Kb,    // [308][1280]
    const u16* __restrict__ Kip,   // [64][1280]
    const u16* __restrict__ Vt,    // [h][d][b][96], cols 77..95 zero
    const u16* __restrict__ VipT,  // [h][d][b][16]
    const float* __restrict__ mask,  // [4096][77]
    u16* __restrict__ Oattn, u16* __restrict__ Oip) {
  const int qt = blockIdx.x, h = blockIdx.y, b = blockIdx.z;
  const int tid = threadIdx.x, l = tid & 63, w = tid >> 6;
  const int lr = l & 15, lg = l >> 4;
  const int r0 = w * 16;
  const int m0 = b * 4096 + qt * 128;

  __shared__ u16 S[34560];
  u16 (*Ks)[72] = (u16(*)[72]) & S[0];
  const int VT_OFF = 6912, VIP_OFF = 13568;
  u16 (*Ps)[104] = (u16(*)[104]) & S[16128];
  u16 (*P2s)[40] = (u16(*)[40]) & S[29440];

  const u16* qrow = Q + (size_t)(m0 + r0 + lr) * 1280 + h * 64;
  s16x8 aq0 = *(const s16x8*)(qrow + lg * 8);
  s16x8 aq1 = *(const s16x8*)(qrow + 32 + lg * 8);

  for (int s = tid; s < 96 * 8; s += 512) {
    const int row = s >> 3, seg = s & 7;
    int4 v = {0, 0, 0, 0};
    if (row < 77)
      v = *(const int4*)(Kb + (size_t)(b * 77 + row) * 1280 + h * 64 + seg * 8);
    else if (row >= 80)
      v = *(const int4*)(Kip + (size_t)(b * 16 + row - 80) * 1280 + h * 64 + seg * 8);
    *(int4*)&Ks[row][(seg ^ ((row >> 3) & 3)) * 8] = v;
  }
  for (int s = tid; s < 64 * 12; s += 512) {
    const int row = s / 12, c = s % 12;
    *(int4*)&S[VT_OFF + row * 104 + c * 8] =
        *(const int4*)(Vt + ((size_t)(h * 64 + row) * 4 + b) * 96 + c * 8);
  }
  for (int s = tid; s < 64 * 4; s += 512) {
    const int row = s >> 2, c = s & 3;
    int4 v = {0, 0, 0, 0};
    if (c >= 2)
      v = *(const int4*)(VipT + ((size_t)(h * 64 + row) * 4 + b) * 16 + (c - 2) * 8);
    *(int4*)&S[VIP_OFF + row * 40 + c * 8] = v;
  }

  // hoisted mask prefetch: overlap latency with staging drain + QK^T
  float mk[4][5];
#pragma unroll
  for (int r = 0; r < 4; ++r) {
    const int qg = qt * 128 + r0 + lg * 4 + r;
#pragma unroll
    for (int t5 = 0; t5 < 5; ++t5) {
      const int t = t5 * 16 + lr;
      mk[r][t5] = (t < 77) ? mask[qg * 77 + t] : 0.f;
    }
  }
  __syncthreads();

  f32x4 sc[5];
  f32x4 sip = {};
#pragma unroll
  for (int t5 = 0; t5 < 6; ++t5) {
    const int trow = t5 * 16 + lr;
    const int qz = (trow >> 3) & 3;
    s16x8 b0 = *(const s16x8*)&Ks[trow][(lg ^ qz) * 8];
    s16x8 b1 = *(const s16x8*)&Ks[trow][((lg + 4) ^ qz) * 8];
    f32x4 c = {};
    c = mfma_bf16(aq0, b0, c);
    c = mfma_bf16(aq1, b1, c);
    if (t5 < 5) sc[t5] = c; else sip = c;
  }

  // softmax WITHOUT max-subtraction (|S| <= ~18 << 88, f32 exp safe)
#pragma unroll
  for (int r = 0; r < 4; ++r) {
    float p[5], sm = 0.f;
#pragma unroll
    for (int t5 = 0; t5 < 5; ++t5) {
      bool valid = (t5 < 4) | (lr < 13);  // t = t5*16+lr < 77
      p[t5] = valid ? __expf(sc[t5][r]) : 0.f;
      sm += p[t5];
    }
    sm += __shfl_xor(sm, 1);
    sm += __shfl_xor(sm, 2);
    sm += __shfl_xor(sm, 4);
    sm += __shfl_xor(sm, 8);
    const float inv = 1.0f / sm;
    const int row = r0 + lg * 4 + r;
#pragma unroll
    for (int t5 = 0; t5 < 5; ++t5)
      Ps[row][t5 * 16 + lr] = f2b(p[t5] * inv * mk[r][t5]);
    Ps[row][80 + lr] = 0;

    float pi = __expf(sip[r]);
    float s2 = pi;
    s2 += __shfl_xor(s2, 1);
    s2 += __shfl_xor(s2, 2);
    s2 += __shfl_xor(s2, 4);
    s2 += __shfl_xor(s2, 8);
    P2s[row][lr] = 0;
    P2s[row][16 + lr] = f2b(pi / s2);
  }

  s16x8 ap[3];
#pragma unroll
  for (int ks = 0; ks < 3; ++ks)
    ap[ks] = *(const s16x8*)&Ps[r0 + lr][ks * 32 + lg * 8];
  s16x8 aip = *(const s16x8*)&P2s[r0 + lr][lg * 8];

  f32x4 om[4], oi[4];
#pragma unroll
  for (int nt = 0; nt < 4; ++nt) {
    const int vrow = nt * 16 + lr;
    f32x4 o = {};
#pragma unroll
    for (int ks = 0; ks < 3; ++ks) {
      s16x8 bv = *(const s16x8*)&S[VT_OFF + vrow * 104 + (ks * 4 + lg) * 8];
      o = mfma_bf16(ap[ks], bv, o);
    }
    s16x8 bip = *(const s16x8*)&S[VIP_OFF + vrow * 40 + lg * 8];
    f32x4 o2 = {};
    o2 = mfma_bf16(aip, bip, o2);
    om[nt] = o;
    oi[nt] = o2;
  }

  __syncthreads();  // all reads of Ks/VT/Ps done: reuse arena for output repack

  u16 (*Om)[72] = (u16(*)[72]) & S[0];
  u16 (*Oi)[72] = (u16(*)[72]) & S[16128];
#pragma unroll
  for (int nt = 0; nt < 4; ++nt)
#pragma unroll
    for (int r = 0; r < 4; ++r) {
      const int row = r0 + lg * 4 + r;
      const int d = nt * 16 + lr;
      Om[row][d] = f2b(om[nt][r]);
      Oi[row][d] = f2b(oi[nt][r]);
    }
  __syncthreads();

  for (int s = tid; s < 128 * 8; s += 512) {
    const int row = s >> 3, seg = s & 7;
    const size_t g = (size_t)(m0 + row) * 1280 + h * 64 + seg * 8;
    *(int4*)(Oattn + g) = *(const int4*)&Om[row][seg * 8];
    *(int4*)(Oip + g) = *(const int4*)&Oi[row][seg * 8];
  }
}

// ---------------- launch ----------------
extern "C" void kernel_launch(void* const* d_in, const int* in_sizes, int n_in,
                              void* d_out, int out_size, void* d_ws, size_t ws_size,
                              hipStream_t stream) {
  (void)in_sizes; (void)n_in; (void)out_size; (void)ws_size;
  const float* hs   = (const float*)d_in[0];
  const float* ehs  = (const float*)d_in[1];
  const float* iph  = (const float*)d_in[2];
  const float* mask = (const float*)d_in[3];
  const float* Wq   = (const float*)d_in[4];
  const float* Wk   = (const float*)d_in[5];
  const float* Wv   = (const float*)d_in[6];
  const float* Wo   = (const float*)d_in[7];
  const float* bo   = (const float*)d_in[8];
  const float* Wkip = (const float*)d_in[9];
  const float* Wvip = (const float*)d_in[10];
  float* out = (float*)d_out;

  char* ws = (char*)d_ws;
  size_t off = 0;
  auto alloc = [&](size_t bytes) {
    char* p = ws + off;
    off += (bytes + 255) & ~(size_t)255;
    return p;
  };
  u16* hsb   = (u16*)alloc(16384ull * 1280 * 2);  // reused as attn_out
  u16* qbuf  = (u16*)alloc(16384ull * 1280 * 2);
  u16* ipout = (u16*)alloc(16384ull * 1280 * 2);
  u16* WqT   = (u16*)alloc(1280ull * 1280 * 2);
  u16* WoT   = (u16*)alloc(1280ull * 1280 * 2);
  u16* WkT   = (u16*)alloc(1280ull * 2048 * 2);
  u16* WvT   = (u16*)alloc(1280ull * 2048 * 2);
  u16* WkipT = (u16*)alloc(1280ull * 2048 * 2);
  u16* WvipT = (u16*)alloc(1280ull * 2048 * 2);
  u16* ehsb  = (u16*)alloc(308ull * 2048 * 2);
  u16* ipb   = (u16*)alloc(64ull * 2048 * 2);
  u16* kbuf  = (u16*)alloc(308ull * 1280 * 2);
  u16* vbuf  = (u16*)alloc(308ull * 1280 * 2);
  u16* kipb  = (u16*)alloc(64ull * 1280 * 2);
  u16* vipb  = (u16*)alloc(64ull * 1280 * 2);
  u16* vt    = (u16*)alloc(1280ull * 4 * 96 * 2);
  u16* vipt  = (u16*)alloc(1280ull * 4 * 16 * 2);

  // merged preprocessing: transposes (z<6) + conversions (z=6)
  k_prep<<<dim3(40, 64, 7), 256, 0, stream>>>(hs, ehs, iph, Wk, Wv, Wkip, Wvip, Wq, Wo,
                                              hsb, ehsb, ipb,
                                              WkT, WvT, WkipT, WvipT, WqT, WoT);

  // Q projection (scale 1/8 baked in): 64 x 4 = 256 blocks, 1/CU
  k_gemm256<0><<<256, 512, 0, stream>>>(hsb, WqT, 1280, 1280, 0.125f,
                                        qbuf, nullptr, nullptr, nullptr, 4);
  // K/V/Kip/Vip projections in one launch (ring-5 prefetch core)
  k_gemm_small4<<<dim3(10, 3, 4), 256, 0, stream>>>(ehsb, ipb, WkT, WvT, WkipT, WvipT,
                                                    kbuf, vbuf, kipb, vipb);
  // V / Vip global transpose for attn's b128 PV path
  k_vtrans<<<dim3(4, 20, 2), 256, 0, stream>>>(vbuf, vipb, vt, vipt);

  // fused attention (main + IP). attn_out -> hsb.
  k_attn<<<dim3(32, 20, 4), 512, 0, stream>>>(qbuf, kbuf, kipb, vt, vipt, mask,
                                              hsb, ipout);

  // out = attn_out @ Wo + bo + ip_out
  k_gemm256<1><<<256, 512, 0, stream>>>(hsb, WoT, 1280, 1280, 1.f,
                                        nullptr, out, bo, ipout, 4);
}

// Round 21
// 252.441 us; speedup vs baseline: 1.0391x; 1.0160x over previous
//
#include <hip/hip_runtime.h>

typedef __attribute__((ext_vector_type(4))) float f32x4;
typedef __attribute__((ext_vector_type(8))) short s16x8;
typedef __attribute__((ext_vector_type(8))) __bf16 bf16x8;
typedef unsigned short u16;

// manual RTNE f32->bf16 (measured faster than the (__bf16) cast path in R19)
__device__ __forceinline__ u16 f2b(float f) {
  union { float f; unsigned u; } x; x.f = f;
  unsigned r = x.u + 0x7fffu + ((x.u >> 16) & 1u);
  return (u16)(r >> 16);
}
__device__ __forceinline__ float b2f(u16 u) {
  union { unsigned u; float f; } x; x.u = ((unsigned)u) << 16;
  return x.f;
}
__device__ __forceinline__ void gld16(const void* g, void* l) {
  __builtin_amdgcn_global_load_lds(
      (const __attribute__((address_space(1))) unsigned int*)g,
      (__attribute__((address_space(3))) unsigned int*)l, 16, 0, 0);
}
__device__ __forceinline__ f32x4 mfma_bf16(s16x8 a, s16x8 b, f32x4 c) {
  return __builtin_amdgcn_mfma_f32_16x16x32_bf16(
      __builtin_bit_cast(bf16x8, a), __builtin_bit_cast(bf16x8, b), c, 0, 0, 0);
}

#define BAR() asm volatile("s_barrier" ::: "memory")

// -------- merged preprocessing. z=0,1: fp32->bf16 convert (dispatched FIRST so the
// BW-bound stream fills the machine); z=2..7: the 6 weight transposes fill in behind.
__global__ void k_prep(const float* __restrict__ hs, const float* __restrict__ ehs,
                       const float* __restrict__ iph,
                       const float* Wk, const float* Wv, const float* Wkip,
                       const float* Wvip, const float* Wq, const float* Wo,
                       u16* __restrict__ hsb, u16* __restrict__ ehsb,
                       u16* __restrict__ ipb,
                       u16* TK, u16* TV, u16* TKip, u16* TVip, u16* TQ, u16* TO) {
  const int z = blockIdx.z;
  if (z >= 2) {
    const int zz = z - 2;
    const float* W = (zz == 0) ? Wk : (zz == 1) ? Wv : (zz == 2) ? Wkip
                    : (zz == 3) ? Wvip : (zz == 4) ? Wq : Wo;
    u16* T = (zz == 0) ? TK : (zz == 1) ? TV : (zz == 2) ? TKip
            : (zz == 3) ? TVip : (zz == 4) ? TQ : TO;
    const int K = (zz < 4) ? 2048 : 1280;
    const int N = 1280;
    __shared__ float tile[32][33];
    int n0 = blockIdx.x * 32, k0 = blockIdx.y * 32;
    if (k0 >= K) return;
    int tx = threadIdx.x & 31, ty = threadIdx.x >> 5;
#pragma unroll
    for (int i = 0; i < 32; i += 8)
      tile[ty + i][tx] = W[(size_t)(k0 + ty + i) * N + n0 + tx];
    __syncthreads();
#pragma unroll
    for (int i = 0; i < 32; i += 8)
      T[(size_t)(n0 + ty + i) * K + k0 + tx] = f2b(tile[tx][ty + i]);
  } else {
    // conversion of hs/ehs/iph: blocks (x, y, z=0..1), dispatched before transposes
    const int n1 = 16384 * 1280 / 4, n2 = 308 * 2048 / 4, n3 = 64 * 2048 / 4;
    const int ntot = n1 + n2 + n3;
    const int stride = 2 * 40 * 64 * 256;
    for (int i = (((z * 64 + blockIdx.y) * 40) + blockIdx.x) * 256 + threadIdx.x;
         i < ntot; i += stride) {
      const float* src; u16* dst; int j = i;
      if (i < n1) { src = hs; dst = hsb; }
      else if (i < n1 + n2) { src = ehs; dst = ehsb; j = i - n1; }
      else { src = iph; dst = ipb; j = i - n1 - n2; }
      float4 v = ((const float4*)src)[j];
      ushort4 o;
      o.x = f2b(v.x); o.y = f2b(v.y); o.z = f2b(v.z); o.w = f2b(v.w);
      ((ushort4*)dst)[j] = o;
    }
  }
}

// ---------------- small-GEMM core (128x128 tile, RING-5 prefetch), K/V projections ---
__device__ __forceinline__ void gemm_core0(
    const u16* __restrict__ A, const u16* __restrict__ BT,
    int M, int N, int K, u16* __restrict__ outb, int m0, int n0) {
  const int tid = threadIdx.x;
  const int l = tid & 63;
  const int w = tid >> 6;
  const int wr = w >> 1, wc = w & 1;
  __shared__ u16 As[5][4096];
  __shared__ u16 Bs[5][4096];
  f32x4 acc[4][4] = {};

  const int o0 = tid * 16;
  const int o1 = o0 + 4096;
  const int ra0 = o0 >> 6, ca0 = (o0 & 63) >> 1;
  const int ra1 = o1 >> 6, ca1 = (o1 & 63) >> 1;
  int ga0 = m0 + ra0; if (ga0 >= M) ga0 = M - 1;
  int ga1 = m0 + ra1; if (ga1 >= M) ga1 = M - 1;
  const u16* Ar0 = A + (size_t)ga0 * K + ca0;
  const u16* Ar1 = A + (size_t)ga1 * K + ca1;
  const u16* Br0 = BT + (size_t)(n0 + ra0) * K + ca0;
  const u16* Br1 = BT + (size_t)(n0 + ra1) * K + ca1;

  const int KT = K >> 5;
#define SSTAGE(s, kt)                                 \
  {                                                   \
    const int k0_ = (kt) << 5;                        \
    gld16(Ar0 + k0_, &As[s][o0 >> 1]);                \
    gld16(Ar1 + k0_, &As[s][o1 >> 1]);                \
    gld16(Br0 + k0_, &Bs[s][o0 >> 1]);                \
    gld16(Br1 + k0_, &Bs[s][o1 >> 1]);                \
  }
  SSTAGE(0, 0);
  SSTAGE(1, 1);
  SSTAGE(2, 2);
  SSTAGE(3, 3);
  asm volatile("s_waitcnt vmcnt(12)" ::: "memory");
  BAR();

  int slot = 0, s4 = 4;
  for (int j = 0; j < KT; ++j) {
    if (j + 4 < KT) SSTAGE(s4, j + 4);
    s16x8 af[4], bfr[4];
#pragma unroll
    for (int mi = 0; mi < 4; ++mi)
      af[mi] = *(const s16x8*)&As[slot][(wr * 64 + mi * 16 + (l & 15)) * 32 + (l >> 4) * 8];
#pragma unroll
    for (int ni = 0; ni < 4; ++ni)
      bfr[ni] = *(const s16x8*)&Bs[slot][(wc * 64 + ni * 16 + (l & 15)) * 32 + (l >> 4) * 8];
#pragma unroll
    for (int mi = 0; mi < 4; ++mi)
#pragma unroll
      for (int ni = 0; ni < 4; ++ni)
        acc[mi][ni] = mfma_bf16(af[mi], bfr[ni], acc[mi][ni]);
    const int rem = KT - 2 - j;
    if (rem >= 3)      asm volatile("s_waitcnt vmcnt(12)" ::: "memory");
    else if (rem == 2) asm volatile("s_waitcnt vmcnt(8)" ::: "memory");
    else if (rem == 1) asm volatile("s_waitcnt vmcnt(4)" ::: "memory");
    else               asm volatile("s_waitcnt vmcnt(0)" ::: "memory");
    BAR();
    ++slot; if (slot >= 5) slot = 0;
    ++s4; if (s4 >= 5) s4 = 0;
  }

#pragma unroll
  for (int mi = 0; mi < 4; ++mi) {
    const int mbase = m0 + wr * 64 + mi * 16 + (l >> 4) * 4;
#pragma unroll
    for (int ni = 0; ni < 4; ++ni) {
      const int ncol = n0 + wc * 64 + ni * 16 + (l & 15);
#pragma unroll
      for (int r = 0; r < 4; ++r) {
        int m = mbase + r;
        if (m < M) outb[(size_t)m * N + ncol] = f2b(acc[mi][ni][r]);
      }
    }
  }
#undef SSTAGE
}

// the four K/V projections in one launch (z selects)
__global__ __launch_bounds__(256) void k_gemm_small4(
    const u16* __restrict__ ehsb, const u16* __restrict__ ipb,
    const u16* __restrict__ WkT, const u16* __restrict__ WvT,
    const u16* __restrict__ WkipT, const u16* __restrict__ WvipT,
    u16* kbuf, u16* vbuf, u16* kipb, u16* vipb) {
  const int z = blockIdx.z;
  const int M = (z < 2) ? 308 : 64;
  const int m0 = blockIdx.y * 128;
  if (m0 >= M) return;
  const u16* A = (z < 2) ? ehsb : ipb;
  const u16* BT = (z == 0) ? WkT : (z == 1) ? WvT : (z == 2) ? WkipT : WvipT;
  u16* out = (z == 0) ? kbuf : (z == 1) ? vbuf : (z == 2) ? kipb : vipb;
  gemm_core0(A, BT, M, 1280, 2048, out, m0, blockIdx.x * 128);
}

// ---------------- V / Vip transpose: [tok][h*64+d] -> vt[h][d][b][96/16] ------------
__global__ void k_vtrans(const u16* __restrict__ vbuf, const u16* __restrict__ vipb,
                         u16* __restrict__ vt, u16* __restrict__ vipt) {
  const int b = blockIdx.x, h = blockIdx.y, z = blockIdx.z;
  const int tid = threadIdx.x;
  __shared__ u16 tile[80][72];
  if (z == 0) {
    for (int s = tid; s < 80 * 8; s += 256) {
      int t = s >> 3, c = s & 7;
      int4 v = {0, 0, 0, 0};
      if (t < 77) v = *(const int4*)(vbuf + (size_t)(b * 77 + t) * 1280 + h * 64 + c * 8);
      *(int4*)&tile[t][c * 8] = v;
    }
    __syncthreads();
    for (int s = tid; s < 64 * 12; s += 256) {
      int d = s / 12, tc = s % 12;
      s16x8 v;
#pragma unroll
      for (int j = 0; j < 8; ++j) {
        int t = tc * 8 + j;
        v[j] = (t < 80) ? (short)tile[t][d] : (short)0;
      }
      *(s16x8*)(vt + ((size_t)(h * 64 + d) * 4 + b) * 96 + tc * 8) = v;
    }
  } else {
    for (int s = tid; s < 16 * 8; s += 256) {
      int t = s >> 3, c = s & 7;
      *(int4*)&tile[t][c * 8] =
          *(const int4*)(vipb + (size_t)(b * 16 + t) * 1280 + h * 64 + c * 8);
    }
    __syncthreads();
    for (int s = tid; s < 64 * 2; s += 256) {
      int d = s >> 1, tc = s & 1;
      s16x8 v;
#pragma unroll
      for (int j = 0; j < 8; ++j) v[j] = (short)tile[tc * 8 + j][d];
      *(s16x8*)(vipt + ((size_t)(h * 64 + d) * 4 + b) * 16 + tc * 8) = v;
    }
  }
}

// ---------------- big GEMM: 256x320 tile, BK=32, RING-4, ONE barrier per K-tile -----
// (R8 schedule verbatim -- best measured: 66 us, MfmaUtil 33, conflicts 0. FROZEN.)
template <int EPI>
__global__ __launch_bounds__(512, 1) void k_gemm256(
    const u16* __restrict__ A, const u16* __restrict__ BT,
    int N, int K, float alpha,
    u16* __restrict__ outb, float* __restrict__ outf,
    const float* __restrict__ bias, const u16* __restrict__ ipadd,
    int nbx) {
  __shared__ u16 lds[73728];
  const int tid = threadIdx.x, l = tid & 63, w = tid >> 6;
  const int lr = l & 15, lg = l >> 4;
  const int wr = w >> 2, wc = w & 3;
  const bool wlo = (w < 4);

  const int nwg = gridDim.x;
  const int q = nwg >> 3, r = nwg & 7;
  const int xcd = blockIdx.x & 7, lid = blockIdx.x >> 3;
  const int wg = (xcd < r) ? (xcd * (q + 1) + lid)
                           : (r * (q + 1) + (xcd - r) * q + lid);
  const int bm0 = (wg / nbx) * 256, bn0 = (wg % nbx) * 320;

  const int srow = tid >> 2;
  const int sslot = ((tid & 3) ^ ((srow >> 1) & 3)) * 8;
  const size_t aO0 = (size_t)(bm0 + srow) * K + sslot;
  const size_t aO1 = aO0 + (size_t)128 * K;
  const size_t bO0 = (size_t)(bn0 + srow) * K + sslot;
  const size_t bO1 = bO0 + (size_t)128 * K;
  const size_t bO2 = bO0 + (size_t)256 * K;
  const int d0 = tid * 8, d1 = (tid + 512) * 8, d2 = (tid + 1024) * 8;

  const int KT = K >> 5;
  f32x4 acc[8][5] = {};
  s16x8 bfv[5], afv[4];

  const int xsw = (lg ^ ((lr >> 1) & 3)) * 8;
  const int aRow = (wr * 128 + lr) * 32 + xsw;
  const int bRow = 32768 + (wc * 80 + lr) * 32 + xsw;

#define STAGE_A(slot, kt)                                              \
  {                                                                    \
    const int base_ = (slot) * 8192;                                   \
    const size_t go_ = (size_t)(kt) * 32;                              \
    gld16(A + aO0 + go_, &lds[base_ + d0]);                            \
    gld16(A + aO1 + go_, &lds[base_ + d1]);                            \
  }
#define STAGE_B(slot, kt)                                              \
  {                                                                    \
    const int base_ = 32768 + (slot) * 10240;                          \
    const size_t go_ = (size_t)(kt) * 32;                              \
    gld16(BT + bO0 + go_, &lds[base_ + d0]);                           \
    gld16(BT + bO1 + go_, &lds[base_ + d1]);                           \
    if (wlo) gld16(BT + bO2 + go_, &lds[base_ + d2]);                  \
  }
#define WAIT_DEEP()                                                    \
  {                                                                    \
    if (wlo) asm volatile("s_waitcnt vmcnt(10)" ::: "memory");         \
    else     asm volatile("s_waitcnt vmcnt(8)" ::: "memory");          \
  }
#define WAIT_MID()                                                     \
  {                                                                    \
    if (wlo) asm volatile("s_waitcnt vmcnt(5)" ::: "memory");          \
    else     asm volatile("s_waitcnt vmcnt(4)" ::: "memory");          \
  }
#define WAITVM0() asm volatile("s_waitcnt vmcnt(0)" ::: "memory")

  STAGE_A(0, 0); STAGE_B(0, 0);
  STAGE_A(1, 1); STAGE_B(1, 1);
  STAGE_A(2, 2); STAGE_B(2, 2);
  WAIT_DEEP();
  BAR();

  for (int j = 0; j < KT; ++j) {
    const int slot = j & 3;
    const int ab = slot * 8192;
    const int bb = slot * 10240;
    const bool pf = (j + 3 < KT);
    const int s3 = (j + 3) & 3;
#pragma unroll
    for (int ni = 0; ni < 5; ++ni)
      bfv[ni] = *(const s16x8*)&lds[bb + bRow + ni * 512];
#pragma unroll
    for (int mi = 0; mi < 4; ++mi)
      afv[mi] = *(const s16x8*)&lds[ab + aRow + mi * 512];
    if (pf) STAGE_A(s3, j + 3);
    __builtin_amdgcn_s_setprio(1);
#pragma unroll
    for (int mi = 0; mi < 4; ++mi)
#pragma unroll
      for (int ni = 0; ni < 5; ++ni)
        acc[mi][ni] = mfma_bf16(afv[mi], bfv[ni], acc[mi][ni]);
    __builtin_amdgcn_s_setprio(0);
#pragma unroll
    for (int mi = 0; mi < 4; ++mi)
      afv[mi] = *(const s16x8*)&lds[ab + aRow + (mi + 4) * 512];
    if (pf) STAGE_B(s3, j + 3);
    __builtin_amdgcn_s_setprio(1);
#pragma unroll
    for (int mi = 0; mi < 4; ++mi)
#pragma unroll
      for (int ni = 0; ni < 5; ++ni)
        acc[mi + 4][ni] = mfma_bf16(afv[mi], bfv[ni], acc[mi + 4][ni]);
    __builtin_amdgcn_s_setprio(0);
    if (pf) { WAIT_DEEP(); }
    else if (j == KT - 3) { WAIT_MID(); }
    else { WAITVM0(); }
    BAR();
  }

  WAITVM0();
  __syncthreads();

  if constexpr (EPI == 0) {
#pragma unroll
    for (int half = 0; half < 2; ++half) {
      if (half) __syncthreads();
      if (wr == half) {
#pragma unroll
        for (int mi = 0; mi < 8; ++mi) {
          const int row = mi * 16 + lg * 4;
#pragma unroll
          for (int ni = 0; ni < 5; ++ni) {
            const int col = wc * 80 + ni * 16 + lr;
#pragma unroll
            for (int rr = 0; rr < 4; ++rr)
              lds[(row + rr) * 320 + col] = f2b(acc[mi][ni][rr] * alpha);
          }
        }
      }
      __syncthreads();
      const int rbase = tid >> 3;
      const int cseg = tid & 7;
#pragma unroll
      for (int rr2 = 0; rr2 < 2; ++rr2)
#pragma unroll
        for (int jj = 0; jj < 5; ++jj) {
          const int row = rr2 * 64 + rbase;
          const int ch = cseg + jj * 8;
          *(int4*)(outb + (size_t)(bm0 + half * 128 + row) * N + bn0 + ch * 8) =
              *(const int4*)&lds[row * 320 + ch * 8];
        }
    }
  } else {
#pragma unroll
    for (int mi = 0; mi < 8; ++mi) {
      const int mrow = bm0 + wr * 128 + mi * 16 + lg * 4;
#pragma unroll
      for (int ni = 0; ni < 5; ++ni) {
        const int ncol = bn0 + wc * 80 + ni * 16 + lr;
#pragma unroll
        for (int rr = 0; rr < 4; ++rr) {
          const size_t idx = (size_t)(mrow + rr) * N + ncol;
          outf[idx] = acc[mi][ni][rr] + bias[ncol] + b2f(ipadd[idx]);
        }
      }
    }
  }
#undef STAGE_A
#undef STAGE_B
#undef WAIT_DEEP
#undef WAIT_MID
#undef WAITVM0
}

// ---------------- fused attention (main + IP): 128 q-rows, no-max softmax, ----------
// hoisted mask prefetch. grid (32, 20, 4), 512 threads.
__global__ __launch_bounds__(512, 4) void k_attn(
    const u16* __restrict__ Q,     // [16384][1280], pre-scaled by 1/8
    const u16* __restrict__ Kb,    // [308][1280]
    const u16* __restrict__ Kip,   // [64][1280]
    const u16* __restrict__ Vt,    // [h][d][b][96], cols 77..95 zero
    const u16* __restrict__ VipT,  // [h][d][b][16]
    const float* __restrict__ mask,  // [4096][77]
    u16* __restrict__ Oattn, u16* __restrict__ Oip) {
  const int qt = blockIdx.x, h = blockIdx.y, b = blockIdx.z;
  const int tid = threadIdx.x, l = tid & 63, w = tid >> 6;
  const int lr = l & 15, lg = l >> 4;
  const int r0 = w * 16;
  const int m0 = b * 4096 + qt * 128;

  __shared__ u16 S[34560];
  u16 (*Ks)[72] = (u16(*)[72]) & S[0];
  const int VT_OFF = 6912, VIP_OFF = 13568;
  u16 (*Ps)[104] = (u16(*)[104]) & S[16128];
  u16 (*P2s)[40] = (u16(*)[40]) & S[29440];

  const u16* qrow = Q + (size_t)(m0 + r0 + lr) * 1280 + h * 64;
  s16x8 aq0 = *(const s16x8*)(qrow + lg * 8);
  s16x8 aq1 = *(const s16x8*)(qrow + 32 + lg * 8);

  for (int s = tid; s < 96 * 8; s += 512) {
    const int row = s >> 3, seg = s & 7;
    int4 v = {0, 0, 0, 0};
    if (row < 77)
      v = *(const int4*)(Kb + (size_t)(b * 77 + row) * 1280 + h * 64 + seg * 8);
    else if (row >= 80)
      v = *(const int4*)(Kip + (size_t)(b * 16 + row - 80) * 1280 + h * 64 + seg * 8);
    *(int4*)&Ks[row][(seg ^ ((row >> 3) & 3)) * 8] = v;
  }
  for (int s = tid; s < 64 * 12; s += 512) {
    const int row = s / 12, c = s % 12;
    *(int4*)&S[VT_OFF + row * 104 + c * 8] =
        *(const int4*)(Vt + ((size_t)(h * 64 + row) * 4 + b) * 96 + c * 8);
  }
  for (int s = tid; s < 64 * 4; s += 512) {
    const int row = s >> 2, c = s & 3;
    int4 v = {0, 0, 0, 0};
    if (c >= 2)
      v = *(const int4*)(VipT + ((size_t)(h * 64 + row) * 4 + b) * 16 + (c - 2) * 8);
    *(int4*)&S[VIP_OFF + row * 40 + c * 8] = v;
  }

  // hoisted mask prefetch: overlap latency with staging drain + QK^T
  float mk[4][5];
#pragma unroll
  for (int r = 0; r < 4; ++r) {
    const int qg = qt * 128 + r0 + lg * 4 + r;
#pragma unroll
    for (int t5 = 0; t5 < 5; ++t5) {
      const int t = t5 * 16 + lr;
      mk[r][t5] = (t < 77) ? mask[qg * 77 + t] : 0.f;
    }
  }
  __syncthreads();

  f32x4 sc[5];
  f32x4 sip = {};
#pragma unroll
  for (int t5 = 0; t5 < 6; ++t5) {
    const int trow = t5 * 16 + lr;
    const int qz = (trow >> 3) & 3;
    s16x8 b0 = *(const s16x8*)&Ks[trow][(lg ^ qz) * 8];
    s16x8 b1 = *(const s16x8*)&Ks[trow][((lg + 4) ^ qz) * 8];
    f32x4 c = {};
    c = mfma_bf16(aq0, b0, c);
    c = mfma_bf16(aq1, b1, c);
    if (t5 < 5) sc[t5] = c; else sip = c;
  }

  // softmax WITHOUT max-subtraction (|S| <= ~18 << 88, f32 exp safe)
#pragma unroll
  for (int r = 0; r < 4; ++r) {
    float p[5], sm = 0.f;
#pragma unroll
    for (int t5 = 0; t5 < 5; ++t5) {
      bool valid = (t5 < 4) | (lr < 13);  // t = t5*16+lr < 77
      p[t5] = valid ? __expf(sc[t5][r]) : 0.f;
      sm += p[t5];
    }
    sm += __shfl_xor(sm, 1);
    sm += __shfl_xor(sm, 2);
    sm += __shfl_xor(sm, 4);
    sm += __shfl_xor(sm, 8);
    const float inv = 1.0f / sm;
    const int row = r0 + lg * 4 + r;
#pragma unroll
    for (int t5 = 0; t5 < 5; ++t5)
      Ps[row][t5 * 16 + lr] = f2b(p[t5] * inv * mk[r][t5]);
    Ps[row][80 + lr] = 0;

    float pi = __expf(sip[r]);
    float s2 = pi;
    s2 += __shfl_xor(s2, 1);
    s2 += __shfl_xor(s2, 2);
    s2 += __shfl_xor(s2, 4);
    s2 += __shfl_xor(s2, 8);
    P2s[row][lr] = 0;
    P2s[row][16 + lr] = f2b(pi / s2);
  }

  s16x8 ap[3];
#pragma unroll
  for (int ks = 0; ks < 3; ++ks)
    ap[ks] = *(const s16x8*)&Ps[r0 + lr][ks * 32 + lg * 8];
  s16x8 aip = *(const s16x8*)&P2s[r0 + lr][lg * 8];

  f32x4 om[4], oi[4];
#pragma unroll
  for (int nt = 0; nt < 4; ++nt) {
    const int vrow = nt * 16 + lr;
    f32x4 o = {};
#pragma unroll
    for (int ks = 0; ks < 3; ++ks) {
      s16x8 bv = *(const s16x8*)&S[VT_OFF + vrow * 104 + (ks * 4 + lg) * 8];
      o = mfma_bf16(ap[ks], bv, o);
    }
    s16x8 bip = *(const s16x8*)&S[VIP_OFF + vrow * 40 + lg * 8];
    f32x4 o2 = {};
    o2 = mfma_bf16(aip, bip, o2);
    om[nt] = o;
    oi[nt] = o2;
  }

  __syncthreads();  // all reads of Ks/VT/Ps done: reuse arena for output repack

  u16 (*Om)[72] = (u16(*)[72]) & S[0];
  u16 (*Oi)[72] = (u16(*)[72]) & S[16128];
#pragma unroll
  for (int nt = 0; nt < 4; ++nt)
#pragma unroll
    for (int r = 0; r < 4; ++r) {
      const int row = r0 + lg * 4 + r;
      const int d = nt * 16 + lr;
      Om[row][d] = f2b(om[nt][r]);
      Oi[row][d] = f2b(oi[nt][r]);
    }
  __syncthreads();

  for (int s = tid; s < 128 * 8; s += 512) {
    const int row = s >> 3, seg = s & 7;
    const size_t g = (size_t)(m0 + row) * 1280 + h * 64 + seg * 8;
    *(int4*)(Oattn + g) = *(const int4*)&Om[row][seg * 8];
    *(int4*)(Oip + g) = *(const int4*)&Oi[row][seg * 8];
  }
}

// ---------------- launch ----------------
extern "C" void kernel_launch(void* const* d_in, const int* in_sizes, int n_in,
                              void* d_out, int out_size, void* d_ws, size_t ws_size,
                              hipStream_t stream) {
  (void)in_sizes; (void)n_in; (void)out_size; (void)ws_size;
  const float* hs   = (const float*)d_in[0];
  const float* ehs  = (const float*)d_in[1];
  const float* iph  = (const float*)d_in[2];
  const float* mask = (const float*)d_in[3];
  const float* Wq   = (const float*)d_in[4];
  const float* Wk   = (const float*)d_in[5];
  const float* Wv   = (const float*)d_in[6];
  const float* Wo   = (const float*)d_in[7];
  const float* bo   = (const float*)d_in[8];
  const float* Wkip = (const float*)d_in[9];
  const float* Wvip = (const float*)d_in[10];
  float* out = (float*)d_out;

  char* ws = (char*)d_ws;
  size_t off = 0;
  auto alloc = [&](size_t bytes) {
    char* p = ws + off;
    off += (bytes + 255) & ~(size_t)255;
    return p;
  };
  u16* hsb   = (u16*)alloc(16384ull * 1280 * 2);  // reused as attn_out
  u16* qbuf  = (u16*)alloc(16384ull * 1280 * 2);
  u16* ipout = (u16*)alloc(16384ull * 1280 * 2);
  u16* WqT   = (u16*)alloc(1280ull * 1280 * 2);
  u16* WoT   = (u16*)alloc(1280ull * 1280 * 2);
  u16* WkT   = (u16*)alloc(1280ull * 2048 * 2);
  u16* WvT   = (u16*)alloc(1280ull * 2048 * 2);
  u16* WkipT = (u16*)alloc(1280ull * 2048 * 2);
  u16* WvipT = (u16*)alloc(1280ull * 2048 * 2);
  u16* ehsb  = (u16*)alloc(308ull * 2048 * 2);
  u16* ipb   = (u16*)alloc(64ull * 2048 * 2);
  u16* kbuf  = (u16*)alloc(308ull * 1280 * 2);
  u16* vbuf  = (u16*)alloc(308ull * 1280 * 2);
  u16* kipb  = (u16*)alloc(64ull * 1280 * 2);
  u16* vipb  = (u16*)alloc(64ull * 1280 * 2);
  u16* vt    = (u16*)alloc(1280ull * 4 * 96 * 2);
  u16* vipt  = (u16*)alloc(1280ull * 4 * 16 * 2);

  // merged preprocessing: conversions (z=0,1 -- dispatched first) + transposes (z=2..7)
  k_prep<<<dim3(40, 64, 8), 256, 0, stream>>>(hs, ehs, iph, Wk, Wv, Wkip, Wvip, Wq, Wo,
                                              hsb, ehsb, ipb,
                                              WkT, WvT, WkipT, WvipT, WqT, WoT);

  // Q projection (scale 1/8 baked in): 64 x 4 = 256 blocks, 1/CU
  k_gemm256<0><<<256, 512, 0, stream>>>(hsb, WqT, 1280, 1280, 0.125f,
                                        qbuf, nullptr, nullptr, nullptr, 4);
  // K/V/Kip/Vip projections in one launch (ring-5 prefetch core)
  k_gemm_small4<<<dim3(10, 3, 4), 256, 0, stream>>>(ehsb, ipb, WkT, WvT, WkipT, WvipT,
                                                    kbuf, vbuf, kipb, vipb);
  // V / Vip global transpose for attn's b128 PV path
  k_vtrans<<<dim3(4, 20, 2), 256, 0, stream>>>(vbuf, vipb, vt, vipt);

  // fused attention (main + IP). attn_out -> hsb.
  k_attn<<<dim3(32, 20, 4), 512, 0, stream>>>(qbuf, kbuf, kipb, vt, vipt, mask,
                                              hsb, ipout);

  // out = attn_out @ Wo + bo + ip_out
  k_gemm256<1><<<256, 512, 0, stream>>>(hsb, WoT, 1280, 1280, 1.f,
                                        nullptr, out, bo, ipout, 4);
}